// Round 7
// baseline (37.403 us; speedup 1.0000x reference)
//
#include <hip/hip_runtime.h>

// MTRNN single step. Live computation after DCE (reference returns only y):
//   io_new = tanh([x|io|cf] @ (0.5*[Wi2io | Wio2io+I | Wcf2io])^T + bsum)
//   y      = tanh(io_new @ Wio2o^T + bio2o)
// cf_new / cs_new dead. bf16 MFMA, f32 accumulate.
// Staging = global_load_lds(16B) into LINEAR LDS; bank conflicts killed by a
// chunk-XOR swizzle baked into the GLOBAL layout/offsets (rule #21), with the
// matching XOR applied on ds_read. 2-phase counted pipeline per K-tile.
// gemm1: BM=64 BN=256 (A-panel read only 2x; pair co-resident on one XCD).

typedef float f32x4 __attribute__((ext_vector_type(4)));
typedef __bf16 bf16x4 __attribute__((ext_vector_type(4)));
typedef __bf16 bf16x8 __attribute__((ext_vector_type(8)));
typedef unsigned short u16x4 __attribute__((ext_vector_type(4)));

__device__ __forceinline__ unsigned short f2bf(float f) {
    unsigned u = __builtin_bit_cast(unsigned, f);
    u += 0x7FFFu + ((u >> 16) & 1u);
    return (unsigned short)(u >> 16);
}

__device__ __forceinline__ float tanh_fast(float x) {
    float e = __expf(2.0f * x);
    return 1.0f - 2.0f * __builtin_amdgcn_rcpf(e + 1.0f);
}

// async global->LDS, 16B per lane. LDS dest must be wave-uniform base.
__device__ __forceinline__ void gload16(const void* g, void* l) {
    __builtin_amdgcn_global_load_lds(
        (const __attribute__((address_space(1))) void*)g,
        (__attribute__((address_space(3))) void*)l, 16, 0, 0);
}

// end-of-tile: wait in-flight stage, then barrier (one drain per tile).
__device__ __forceinline__ void wait_barrier() {
    asm volatile("s_waitcnt vmcnt(0)\n\ts_barrier" ::: "memory");
}

// ---------------------------------------------------------------------------
// Kernel 0: pack weights to bf16, CHUNK-SWIZZLED within each 64-col K-tile:
// element (n,k) -> n*L + (k&~63) + ((((k>>3)&7) ^ (n&7))<<3) + (k&7).
//   wcat[512][1152] = 0.5*[Wi2io | Wio2io + I | Wcf2io]
//   w2s [128][512]  = Wio2o
//   bsum[512]       = 0.5*(bi2io + bio2io + bcf2io)
// ---------------------------------------------------------------------------
__global__ __launch_bounds__(256) void k_convert(
    const float* __restrict__ Wi2io, const float* __restrict__ Wio2io,
    const float* __restrict__ Wcf2io, const float* __restrict__ Wio2o,
    const float* __restrict__ b1, const float* __restrict__ b2,
    const float* __restrict__ b3,
    unsigned short* __restrict__ wcat, unsigned short* __restrict__ w2s,
    float* __restrict__ bsum)
{
    int idx = blockIdx.x * 256 + threadIdx.x;
    if (idx < 147456) {              // 512*1152/4 quads
        int n = idx / 288;
        int k = (idx - n * 288) * 4;
        const float* s;
        if (k < 128)      s = Wi2io  + n * 128 + k;
        else if (k < 640) s = Wio2io + n * 512 + (k - 128);
        else              s = Wcf2io + n * 512 + (k - 640);
        f32x4 v = *(const f32x4*)s;
        u16x4 h;
        #pragma unroll
        for (int t = 0; t < 4; ++t) {
            float f = 0.5f * v[t];
            int kk = k + t;
            if (kk >= 128 && kk < 640 && (kk - 128) == n) f += 0.5f;  // +0.5*I
            h[t] = f2bf(f);
        }
        int ad = n * 1152 + (k & ~63) + ((((k >> 3) & 7) ^ (n & 7)) << 3) + (k & 7);
        *(u16x4*)(wcat + ad) = h;
    } else if (idx < 163840) {       // 128*512/4 quads
        int q = idx - 147456;
        int n = q >> 7;
        int k = (q & 127) * 4;
        f32x4 v = *(const f32x4*)(Wio2o + n * 512 + k);
        u16x4 h; h[0]=f2bf(v[0]); h[1]=f2bf(v[1]); h[2]=f2bf(v[2]); h[3]=f2bf(v[3]);
        int ad = n * 512 + (k & ~63) + ((((k >> 3) & 7) ^ (n & 7)) << 3) + (k & 7);
        *(u16x4*)(w2s + ad) = h;
    } else if (idx < 164352) {
        int n = idx - 163840;
        bsum[n] = 0.5f * (b1[n] + b2[n] + b3[n]);
    }
}

// ---------------------------------------------------------------------------
// Kernel 1: ionew = tanh(Acat @ wcat^T + bsum), bf16 out (stored swizzled).
// M=8192 N=512 K=1152. BM=64 BN=256 BK=64, 512 thr (8 waves 2x4, wave 32x64).
// Grid 256 = 1 block/CU; the 2 col-blocks of each A panel are co-resident on
// the panel's XCD (2nd A read is an L2 hit). LDS 2 x (A 16KB f32 | B 32KB).
// ---------------------------------------------------------------------------
__global__ __launch_bounds__(512, 2) void k_gemm1(
    const float* __restrict__ x, const float* __restrict__ io,
    const float* __restrict__ cf,
    const unsigned short* __restrict__ wcat,
    const float* __restrict__ bsum,
    unsigned short* __restrict__ ionew)
{
    __shared__ __align__(16) char lds[2][49152];   // A @0 (16KB), B @16384 (32KB)

    const int tid = threadIdx.x, b = blockIdx.x;
    // XCD x (= b&7 under round-robin) owns panels [16x,16x+16) x 2 col-blocks.
    const int xcd = b & 7, idx = b >> 3;           // idx 0..31
    const int m0 = ((xcd << 4) | (idx & 15)) << 6; // panel*64
    const int n0 = (idx >> 4) << 8;                // 0 / 256

    const int lane = tid & 63, wid = tid >> 6;
    const int li = lane & 15, lh = lane >> 4;
    const int wm = (wid >> 2) << 5;       // 0/32
    const int wn = (wid & 3) << 6;        // 0/64/128/192

    // staging offsets (swizzle baked into source; constant across K-tiles)
    int a_off_x[2], a_off_s[2], b_off[4];
    #pragma unroll
    for (int j = 0; j < 2; ++j) {
        int r = (wid << 3) + (j << 2) + (lane >> 4);   // A row 0..63
        int cs = ((lane & 15) ^ (r & 15)) << 2;        // swizzled 16B chunk
        a_off_x[j] = (m0 + r) * 128 + cs;
        a_off_s[j] = (m0 + r) * 512 + cs;
    }
    #pragma unroll
    for (int j = 0; j < 4; ++j) {
        int rb = (wid << 5) + (j << 3) + (lane >> 3);  // B row 0..255
        b_off[j] = (n0 + rb) * 1152 + ((lane & 7) << 3);  // linear (pre-swz)
    }
    const int adstA = wid << 11;   // 2KB/wave in A region
    const int adstB = wid << 12;   // 4KB/wave in B region

    f32x4 zz = {0.f, 0.f, 0.f, 0.f};
    f32x4 acc[2][4];
    #pragma unroll
    for (int i = 0; i < 2; ++i)
        #pragma unroll
        for (int j = 0; j < 4; ++j) acc[i][j] = zz;

#define STAGE1(KT, BUF) do {                                                   \
        int K_ = (KT);                                                         \
        char* A_ = (BUF); char* B_ = (BUF) + 16384;                            \
        if (K_ < 2) {                                                          \
            const float* sp = x + (K_ << 6);                                   \
            _Pragma("unroll")                                                  \
            for (int j = 0; j < 2; ++j)                                        \
                gload16(sp + a_off_x[j], A_ + adstA + (j << 10));              \
        } else if (K_ < 10) {                                                  \
            const float* sp = io + ((K_ - 2) << 6);                            \
            _Pragma("unroll")                                                  \
            for (int j = 0; j < 2; ++j)                                        \
                gload16(sp + a_off_s[j], A_ + adstA + (j << 10));              \
        } else {                                                               \
            const float* sp = cf + ((K_ - 10) << 6);                           \
            _Pragma("unroll")                                                  \
            for (int j = 0; j < 2; ++j)                                        \
                gload16(sp + a_off_s[j], A_ + adstA + (j << 10));              \
        }                                                                      \
        const unsigned short* wp = wcat + (K_ << 6);                           \
        _Pragma("unroll")                                                      \
        for (int j = 0; j < 4; ++j)                                            \
            gload16(wp + b_off[j], B_ + adstB + (j << 10));                    \
    } while (0)

#define COMPUTE1(BUF) do {                                                     \
        const char* A_ = (BUF); const char* B_ = (BUF) + 16384;                \
        _Pragma("unroll")                                                      \
        for (int ks = 0; ks < 2; ++ks) {                                       \
            bf16x8 af[2];                                                      \
            _Pragma("unroll")                                                  \
            for (int mi = 0; mi < 2; ++mi) {                                   \
                int r = wm + mi * 16 + li;                                     \
                int c0 = ks * 8 + lh * 2;                                      \
                f32x4 a0 = *(const f32x4*)(A_ + r * 256 +                      \
                                           ((c0 ^ (r & 15)) << 4));            \
                f32x4 a1 = *(const f32x4*)(A_ + r * 256 +                      \
                                           (((c0 + 1) ^ (r & 15)) << 4));      \
                bf16x4 h0 = __builtin_convertvector(a0, bf16x4);               \
                bf16x4 h1 = __builtin_convertvector(a1, bf16x4);               \
                af[mi] = __builtin_shufflevector(h0, h1, 0,1,2,3,4,5,6,7);     \
            }                                                                  \
            _Pragma("unroll")                                                  \
            for (int nj = 0; nj < 4; ++nj) {                                   \
                int rb = wn + nj * 16 + li;                                    \
                int cb = ks * 4 + lh;                                          \
                bf16x8 bv = *(const bf16x8*)(B_ + rb * 128 +                   \
                                             ((cb ^ (rb & 7)) << 4));          \
                acc[0][nj] = __builtin_amdgcn_mfma_f32_16x16x32_bf16(          \
                    af[0], bv, acc[0][nj], 0, 0, 0);                           \
                acc[1][nj] = __builtin_amdgcn_mfma_f32_16x16x32_bf16(          \
                    af[1], bv, acc[1][nj], 0, 0, 0);                           \
            }                                                                  \
        }                                                                      \
    } while (0)

    STAGE1(0, lds[0]);
    wait_barrier();
    #pragma unroll 1
    for (int kt = 0; kt < 18; ++kt) {
        if (kt + 1 < 18) STAGE1(kt + 1, lds[(kt + 1) & 1]);
        COMPUTE1(lds[kt & 1]);
        wait_barrier();
    }
#undef STAGE1
#undef COMPUTE1

    // epilogue: bias+tanh, store bf16 chunk-swizzled (gemm2-ready layout)
    #pragma unroll
    for (int nj = 0; nj < 4; ++nj) {
        int gn = n0 + wn + nj * 16 + li;
        float bb = bsum[gn];
        #pragma unroll
        for (int mi = 0; mi < 2; ++mi) {
            #pragma unroll
            for (int r = 0; r < 4; ++r) {
                int gm = m0 + wm + mi * 16 + (lh << 2) + r;
                float v = tanh_fast(acc[mi][nj][r] + bb);
                int ad = gm * 512 + (gn & ~63) +
                         ((((gn >> 3) & 7) ^ (gm & 7)) << 3) + (gn & 7);
                ionew[ad] = f2bf(v);
            }
        }
    }
}

// ---------------------------------------------------------------------------
// Kernel 2: y = tanh(ionew @ w2s^T + bio2o). M=8192 N=128 K=512.
// BM=32 BN=128(full) BK=64, 256 thr (4 waves, wave 32x32). Grid 256.
// Both operands pre-swizzled bf16 -> linear gl_lds staging.
// ---------------------------------------------------------------------------
__global__ __launch_bounds__(256, 2) void k_gemm2(
    const unsigned short* __restrict__ ionew,
    const unsigned short* __restrict__ w2s,
    const float* __restrict__ b4,
    float* __restrict__ out)
{
    __shared__ __align__(16) char lds[2][20480];   // A @0 (4KB), B @4096 (16KB)

    const int tid = threadIdx.x, b = blockIdx.x;
    const int xcd = b & 7, idx = b >> 3;           // idx 0..31
    const int m0 = ((xcd << 5) | idx) << 5;        // matches gemm1 writer XCD

    const int lane = tid & 63, wid = tid >> 6;
    const int li = lane & 15, lh = lane >> 4;
    const int wn = wid << 5;                       // 32 out-cols per wave

    const int a2_off = (m0 + (wid << 3) + (lane >> 3)) * 512 + ((lane & 7) << 3);
    int b2_off[4];
    #pragma unroll
    for (int j = 0; j < 4; ++j)
        b2_off[j] = ((wid << 5) + 8 * j + (lane >> 3)) * 512 + ((lane & 7) << 3);

    f32x4 zz = {0.f, 0.f, 0.f, 0.f};
    f32x4 acc[2][2];
    acc[0][0] = zz; acc[0][1] = zz; acc[1][0] = zz; acc[1][1] = zz;

#define STAGE2(KT, BUF) do {                                                   \
        int K_ = (KT);                                                         \
        char* A_ = (BUF); char* B_ = (BUF) + 4096;                             \
        gload16(ionew + a2_off + (K_ << 6), A_ + (wid << 10));                 \
        _Pragma("unroll")                                                      \
        for (int j = 0; j < 4; ++j)                                            \
            gload16(w2s + b2_off[j] + (K_ << 6), B_ + (wid << 12) + j * 1024); \
    } while (0)

#define COMPUTE2(BUF) do {                                                     \
        const char* A_ = (BUF); const char* B_ = (BUF) + 4096;                 \
        _Pragma("unroll")                                                      \
        for (int ks = 0; ks < 2; ++ks) {                                       \
            int c = ks * 4 + lh;                                               \
            bf16x8 av[2];                                                      \
            _Pragma("unroll")                                                  \
            for (int mi = 0; mi < 2; ++mi) {                                   \
                int r = mi * 16 + li;                                          \
                av[mi] = *(const bf16x8*)(A_ + r * 128 + ((c ^ (r & 7)) << 4));\
            }                                                                  \
            _Pragma("unroll")                                                  \
            for (int nj = 0; nj < 2; ++nj) {                                   \
                int rb = wn + nj * 16 + li;                                    \
                bf16x8 bv = *(const bf16x8*)(B_ + rb * 128 +                   \
                                             ((c ^ (rb & 7)) << 4));           \
                acc[0][nj] = __builtin_amdgcn_mfma_f32_16x16x32_bf16(          \
                    av[0], bv, acc[0][nj], 0, 0, 0);                           \
                acc[1][nj] = __builtin_amdgcn_mfma_f32_16x16x32_bf16(          \
                    av[1], bv, acc[1][nj], 0, 0, 0);                           \
            }                                                                  \
        }                                                                      \
    } while (0)

    STAGE2(0, lds[0]);
    wait_barrier();
    #pragma unroll 1
    for (int kt = 0; kt < 8; ++kt) {
        if (kt + 1 < 8) STAGE2(kt + 1, lds[(kt + 1) & 1]);
        COMPUTE2(lds[kt & 1]);
        wait_barrier();
    }
#undef STAGE2
#undef COMPUTE2

    #pragma unroll
    for (int nj = 0; nj < 2; ++nj) {
        int n = wn + nj * 16 + li;
        float bb = b4[n];
        #pragma unroll
        for (int mi = 0; mi < 2; ++mi) {
            #pragma unroll
            for (int r = 0; r < 4; ++r) {
                int gm = m0 + mi * 16 + (lh << 2) + r;
                out[(size_t)gm * 128 + n] = tanh_fast(acc[mi][nj][r] + bb);
            }
        }
    }
}

// ---------------------------------------------------------------------------
extern "C" void kernel_launch(void* const* d_in, const int* in_sizes, int n_in,
                              void* d_out, int out_size, void* d_ws, size_t ws_size,
                              hipStream_t stream)
{
    const float* x      = (const float*)d_in[0];
    const float* io     = (const float*)d_in[1];
    const float* cf     = (const float*)d_in[2];
    // d_in[3] cs_state: dead (does not feed y)
    const float* Wi2io  = (const float*)d_in[4];
    const float* bi2io  = (const float*)d_in[5];
    const float* Wio2o  = (const float*)d_in[6];
    const float* bio2o  = (const float*)d_in[7];
    const float* Wio2io = (const float*)d_in[8];
    const float* bio2io = (const float*)d_in[9];
    const float* Wcf2io = (const float*)d_in[12];
    const float* bcf2io = (const float*)d_in[13];
    float* out = (float*)d_out;

    // ws: wcat 1,179,648 | w2s 131,072 | bsum 2,048 | ionew 8,388,608
    char* ws = (char*)d_ws;
    unsigned short* wcat  = (unsigned short*)ws;
    unsigned short* w2s   = (unsigned short*)(ws + 1179648);
    float*          bsum  = (float*)(ws + 1310720);
    unsigned short* ionew = (unsigned short*)(ws + 1312768);

    hipLaunchKernelGGL(k_convert, dim3(642), dim3(256), 0, stream,
                       Wi2io, Wio2io, Wcf2io, Wio2o, bi2io, bio2io, bcf2io,
                       wcat, w2s, bsum);
    hipLaunchKernelGGL(k_gemm1, dim3(256), dim3(512), 0, stream,
                       x, io, cf, wcat, bsum, ionew);
    hipLaunchKernelGGL(k_gemm2, dim3(256), dim3(256), 0, stream,
                       ionew, w2s, bio2o, out);
}

// Round 8
// 32.884 us; speedup vs baseline: 1.1374x; 1.1374x over previous
//
#include <hip/hip_runtime.h>

// MTRNN single step. Live computation after DCE (reference returns only y):
//   io_new = tanh([x|io|cf] @ (0.5*[Wi2io | Wio2io+I | Wcf2io])^T + bsum)
//   y      = tanh(io_new @ Wio2o^T + bio2o)
// cf_new / cs_new dead. bf16 MFMA, f32 accumulate.
// Staging = global_load_lds(16B) into LINEAR LDS; bank conflicts killed by a
// chunk-XOR swizzle baked into the GLOBAL layout/offsets (rule #21), matching
// XOR applied on ds_read. T4 pipeline: 3 LDS buffers, loads issued 2 tiles
// ahead, counted s_waitcnt vmcnt(N) (never 0 in the main loop).

typedef float f32x4 __attribute__((ext_vector_type(4)));
typedef __bf16 bf16x4 __attribute__((ext_vector_type(4)));
typedef __bf16 bf16x8 __attribute__((ext_vector_type(8)));
typedef unsigned short u16x4 __attribute__((ext_vector_type(4)));

__device__ __forceinline__ unsigned short f2bf(float f) {
    unsigned u = __builtin_bit_cast(unsigned, f);
    u += 0x7FFFu + ((u >> 16) & 1u);
    return (unsigned short)(u >> 16);
}

__device__ __forceinline__ float tanh_fast(float x) {
    float e = __expf(2.0f * x);
    return 1.0f - 2.0f * __builtin_amdgcn_rcpf(e + 1.0f);
}

// async global->LDS, 16B per lane. LDS dest is wave-uniform base + lane*16.
__device__ __forceinline__ void gload16(const void* g, void* l) {
    __builtin_amdgcn_global_load_lds(
        (const __attribute__((address_space(1))) void*)g,
        (__attribute__((address_space(3))) void*)l, 16, 0, 0);
}

// counted wait + barrier: tile t's loads retired, deeper tiles stay in flight.
#define WAITB(N) asm volatile("s_waitcnt vmcnt(" #N ")\n\ts_barrier" ::: "memory")

// ---------------------------------------------------------------------------
// Kernel 0: pack weights to bf16, CHUNK-SWIZZLED within each 64-col K-tile:
// element (n,k) -> n*L + (k&~63) + ((((k>>3)&7) ^ (n&7))<<3) + (k&7).
//   wcat[512][1152] = 0.5*[Wi2io | Wio2io + I | Wcf2io]
//   w2s [128][512]  = Wio2o
//   bsum[512]       = 0.5*(bi2io + bio2io + bcf2io)
// ---------------------------------------------------------------------------
__global__ __launch_bounds__(256) void k_convert(
    const float* __restrict__ Wi2io, const float* __restrict__ Wio2io,
    const float* __restrict__ Wcf2io, const float* __restrict__ Wio2o,
    const float* __restrict__ b1, const float* __restrict__ b2,
    const float* __restrict__ b3,
    unsigned short* __restrict__ wcat, unsigned short* __restrict__ w2s,
    float* __restrict__ bsum)
{
    int idx = blockIdx.x * 256 + threadIdx.x;
    if (idx < 147456) {              // 512*1152/4 quads
        int n = idx / 288;
        int k = (idx - n * 288) * 4;
        const float* s;
        if (k < 128)      s = Wi2io  + n * 128 + k;
        else if (k < 640) s = Wio2io + n * 512 + (k - 128);
        else              s = Wcf2io + n * 512 + (k - 640);
        f32x4 v = *(const f32x4*)s;
        u16x4 h;
        #pragma unroll
        for (int t = 0; t < 4; ++t) {
            float f = 0.5f * v[t];
            int kk = k + t;
            if (kk >= 128 && kk < 640 && (kk - 128) == n) f += 0.5f;  // +0.5*I
            h[t] = f2bf(f);
        }
        int ad = n * 1152 + (k & ~63) + ((((k >> 3) & 7) ^ (n & 7)) << 3) + (k & 7);
        *(u16x4*)(wcat + ad) = h;
    } else if (idx < 163840) {       // 128*512/4 quads
        int q = idx - 147456;
        int n = q >> 7;
        int k = (q & 127) * 4;
        f32x4 v = *(const f32x4*)(Wio2o + n * 512 + k);
        u16x4 h; h[0]=f2bf(v[0]); h[1]=f2bf(v[1]); h[2]=f2bf(v[2]); h[3]=f2bf(v[3]);
        int ad = n * 512 + (k & ~63) + ((((k >> 3) & 7) ^ (n & 7)) << 3) + (k & 7);
        *(u16x4*)(w2s + ad) = h;
    } else if (idx < 164352) {
        int n = idx - 163840;
        bsum[n] = 0.5f * (b1[n] + b2[n] + b3[n]);
    }
}

// ---------------------------------------------------------------------------
// Kernel 1: ionew = tanh(Acat @ wcat^T + bsum), bf16 out (stored swizzled).
// M=8192 N=512 K=1152. BM=128 BN=128 BK=64, 512 thr (8 waves 4m x 2n, wave
// 32x64). Grid 256 = 1 block/CU, XCD-affine (8 panels x 4 colb per XCD).
// LDS 3 x (A 128x64 f32 32KB | B 128x64 bf16 16KB) = 144KB.
// Pipeline: loads 2 tiles ahead, vmcnt(6) steady-state wait.
// ---------------------------------------------------------------------------
__global__ __launch_bounds__(512, 2) void k_gemm1(
    const float* __restrict__ x, const float* __restrict__ io,
    const float* __restrict__ cf,
    const unsigned short* __restrict__ wcat,
    const float* __restrict__ bsum,
    unsigned short* __restrict__ ionew)
{
    __shared__ __align__(16) char lds[3][49152];   // A @0 (32KB), B @32768

    const int tid = threadIdx.x, b = blockIdx.x;
    const int xcd = b & 7, idx = b >> 3;           // idx 0..31
    const int m0 = ((xcd << 3) | (idx & 7)) << 7;  // panel*128
    const int n0 = (idx >> 3) << 7;                // colb*128

    const int lane = tid & 63, wid = tid >> 6;
    const int li = lane & 15, lh = lane >> 4;
    const int wm = (wid >> 1) << 5;       // 0/32/64/96
    const int wn = (wid & 1) << 6;        // 0/64

    // staging offsets (swizzle baked into source; constant across K-tiles)
    int a_off_x[4], a_off_s[4], b_off[2];
    #pragma unroll
    for (int j = 0; j < 4; ++j) {
        int r = (wid << 4) + (j << 2) + (lane >> 4);     // A row 0..127
        int cs = ((lane & 15) ^ (r & 15)) << 2;          // swizzled 16B chunk
        a_off_x[j] = (m0 + r) * 128 + cs;
        a_off_s[j] = (m0 + r) * 512 + cs;
    }
    #pragma unroll
    for (int j = 0; j < 2; ++j) {
        int rb = ((wid << 1) + j) * 8 + (lane >> 3);     // B row 0..127
        b_off[j] = (n0 + rb) * 1152 + ((lane & 7) << 3); // linear (pre-swz)
    }
    const int adstA = wid << 12;   // + j<<10 : 4 x 1KB per wave
    const int adstB = wid << 11;   // + j<<10 : 2 x 1KB per wave

    f32x4 zz = {0.f, 0.f, 0.f, 0.f};
    f32x4 acc[2][4];
    #pragma unroll
    for (int i = 0; i < 2; ++i)
        #pragma unroll
        for (int j = 0; j < 4; ++j) acc[i][j] = zz;

#define STAGE1(KT, BUF) do {                                                   \
        int K_ = (KT);                                                         \
        char* A_ = (BUF); char* B_ = (BUF) + 32768;                            \
        if (K_ < 2) {                                                          \
            const float* sp = x + (K_ << 6);                                   \
            _Pragma("unroll")                                                  \
            for (int j = 0; j < 4; ++j)                                        \
                gload16(sp + a_off_x[j], A_ + adstA + (j << 10));              \
        } else if (K_ < 10) {                                                  \
            const float* sp = io + ((K_ - 2) << 6);                            \
            _Pragma("unroll")                                                  \
            for (int j = 0; j < 4; ++j)                                        \
                gload16(sp + a_off_s[j], A_ + adstA + (j << 10));              \
        } else {                                                               \
            const float* sp = cf + ((K_ - 10) << 6);                           \
            _Pragma("unroll")                                                  \
            for (int j = 0; j < 4; ++j)                                        \
                gload16(sp + a_off_s[j], A_ + adstA + (j << 10));              \
        }                                                                      \
        const unsigned short* wp = wcat + (K_ << 6);                           \
        _Pragma("unroll")                                                      \
        for (int j = 0; j < 2; ++j)                                            \
            gload16(wp + b_off[j], B_ + adstB + (j << 10));                    \
    } while (0)

#define COMPUTE1(BUF) do {                                                     \
        const char* A_ = (BUF); const char* B_ = (BUF) + 32768;                \
        _Pragma("unroll")                                                      \
        for (int ks = 0; ks < 2; ++ks) {                                       \
            bf16x8 af[2];                                                      \
            _Pragma("unroll")                                                  \
            for (int mi = 0; mi < 2; ++mi) {                                   \
                int r = wm + mi * 16 + li;                                     \
                int c0 = ks * 8 + lh * 2;                                      \
                f32x4 a0 = *(const f32x4*)(A_ + r * 256 +                      \
                                           ((c0 ^ (r & 15)) << 4));            \
                f32x4 a1 = *(const f32x4*)(A_ + r * 256 +                      \
                                           (((c0 + 1) ^ (r & 15)) << 4));      \
                bf16x4 h0 = __builtin_convertvector(a0, bf16x4);               \
                bf16x4 h1 = __builtin_convertvector(a1, bf16x4);               \
                af[mi] = __builtin_shufflevector(h0, h1, 0,1,2,3,4,5,6,7);     \
            }                                                                  \
            _Pragma("unroll")                                                  \
            for (int nj = 0; nj < 4; ++nj) {                                   \
                int rb = wn + nj * 16 + li;                                    \
                int cb = ks * 4 + lh;                                          \
                bf16x8 bv = *(const bf16x8*)(B_ + rb * 128 +                   \
                                             ((cb ^ (rb & 7)) << 4));          \
                acc[0][nj] = __builtin_amdgcn_mfma_f32_16x16x32_bf16(          \
                    af[0], bv, acc[0][nj], 0, 0, 0);                           \
                acc[1][nj] = __builtin_amdgcn_mfma_f32_16x16x32_bf16(          \
                    af[1], bv, acc[1][nj], 0, 0, 0);                           \
            }                                                                  \
        }                                                                      \
    } while (0)

    STAGE1(0, lds[0]);
    STAGE1(1, lds[1]);
    char* p0 = lds[0]; char* p1 = lds[1]; char* p2 = lds[2];
    #pragma unroll 1
    for (int t = 0; t < 17; ++t) {
        WAITB(6);                          // tile t retired; t+1 in flight
        if (t + 2 < 18) STAGE1(t + 2, p2); // 2 tiles ahead
        COMPUTE1(p0);
        char* tmp = p0; p0 = p1; p1 = p2; p2 = tmp;
    }
    WAITB(0);
    COMPUTE1(p0);                          // tile 17
#undef STAGE1
#undef COMPUTE1

    // epilogue: bias+tanh, store bf16 chunk-swizzled (gemm2-ready layout)
    #pragma unroll
    for (int nj = 0; nj < 4; ++nj) {
        int gn = n0 + wn + nj * 16 + li;
        float bb = bsum[gn];
        #pragma unroll
        for (int mi = 0; mi < 2; ++mi) {
            #pragma unroll
            for (int r = 0; r < 4; ++r) {
                int gm = m0 + wm + mi * 16 + (lh << 2) + r;
                float v = tanh_fast(acc[mi][nj][r] + bb);
                int ad = gm * 512 + (gn & ~63) +
                         ((((gn >> 3) & 7) ^ (gm & 7)) << 3) + (gn & 7);
                ionew[ad] = f2bf(v);
            }
        }
    }
}

// ---------------------------------------------------------------------------
// Kernel 2: y = tanh(ionew @ w2s^T + bio2o). M=8192 N=128 K=512.
// BM=32 BN=128(full) BK=64, 256 thr (4 waves, wave 32x32). Grid 256.
// Same 3-buffer counted pipeline (5 loads/stage -> vmcnt(5)).
// ---------------------------------------------------------------------------
__global__ __launch_bounds__(256, 2) void k_gemm2(
    const unsigned short* __restrict__ ionew,
    const unsigned short* __restrict__ w2s,
    const float* __restrict__ b4,
    float* __restrict__ out)
{
    __shared__ __align__(16) char lds[3][20480];   // A @0 (4KB), B @4096 (16KB)

    const int tid = threadIdx.x, b = blockIdx.x;
    const int xcd = b & 7, idx = b >> 3;           // idx 0..31
    const int m0 = ((xcd << 5) | idx) << 5;        // matches gemm1 writer XCD

    const int lane = tid & 63, wid = tid >> 6;
    const int li = lane & 15, lh = lane >> 4;
    const int wn = wid << 5;                       // 32 out-cols per wave

    const int a2_off = (m0 + (wid << 3) + (lane >> 3)) * 512 + ((lane & 7) << 3);
    int b2_off[4];
    #pragma unroll
    for (int j = 0; j < 4; ++j)
        b2_off[j] = ((wid << 5) + 8 * j + (lane >> 3)) * 512 + ((lane & 7) << 3);

    f32x4 zz = {0.f, 0.f, 0.f, 0.f};
    f32x4 acc[2][2];
    acc[0][0] = zz; acc[0][1] = zz; acc[1][0] = zz; acc[1][1] = zz;

#define STAGE2(KT, BUF) do {                                                   \
        int K_ = (KT);                                                         \
        char* A_ = (BUF); char* B_ = (BUF) + 4096;                             \
        gload16(ionew + a2_off + (K_ << 6), A_ + (wid << 10));                 \
        _Pragma("unroll")                                                      \
        for (int j = 0; j < 4; ++j)                                            \
            gload16(w2s + b2_off[j] + (K_ << 6), B_ + (wid << 12) + j * 1024); \
    } while (0)

#define COMPUTE2(BUF) do {                                                     \
        const char* A_ = (BUF); const char* B_ = (BUF) + 4096;                 \
        _Pragma("unroll")                                                      \
        for (int ks = 0; ks < 2; ++ks) {                                       \
            int c = ks * 4 + lh;                                               \
            bf16x8 av[2];                                                      \
            _Pragma("unroll")                                                  \
            for (int mi = 0; mi < 2; ++mi) {                                   \
                int r = mi * 16 + li;                                          \
                av[mi] = *(const bf16x8*)(A_ + r * 128 + ((c ^ (r & 7)) << 4));\
            }                                                                  \
            _Pragma("unroll")                                                  \
            for (int nj = 0; nj < 2; ++nj) {                                   \
                int rb = wn + nj * 16 + li;                                    \
                bf16x8 bv = *(const bf16x8*)(B_ + rb * 128 +                   \
                                             ((c ^ (rb & 7)) << 4));           \
                acc[0][nj] = __builtin_amdgcn_mfma_f32_16x16x32_bf16(          \
                    av[0], bv, acc[0][nj], 0, 0, 0);                           \
                acc[1][nj] = __builtin_amdgcn_mfma_f32_16x16x32_bf16(          \
                    av[1], bv, acc[1][nj], 0, 0, 0);                           \
            }                                                                  \
        }                                                                      \
    } while (0)

    STAGE2(0, lds[0]);
    STAGE2(1, lds[1]);
    char* p0 = lds[0]; char* p1 = lds[1]; char* p2 = lds[2];
    #pragma unroll 1
    for (int t = 0; t < 7; ++t) {
        WAITB(5);
        if (t + 2 < 8) STAGE2(t + 2, p2);
        COMPUTE2(p0);
        char* tmp = p0; p0 = p1; p1 = p2; p2 = tmp;
    }
    WAITB(0);
    COMPUTE2(p0);                          // tile 7
#undef STAGE2
#undef COMPUTE2

    #pragma unroll
    for (int nj = 0; nj < 2; ++nj) {
        int n = wn + nj * 16 + li;
        float bb = b4[n];
        #pragma unroll
        for (int mi = 0; mi < 2; ++mi) {
            #pragma unroll
            for (int r = 0; r < 4; ++r) {
                int gm = m0 + mi * 16 + (lh << 2) + r;
                out[(size_t)gm * 128 + n] = tanh_fast(acc[mi][nj][r] + bb);
            }
        }
    }
}

// ---------------------------------------------------------------------------
extern "C" void kernel_launch(void* const* d_in, const int* in_sizes, int n_in,
                              void* d_out, int out_size, void* d_ws, size_t ws_size,
                              hipStream_t stream)
{
    const float* x      = (const float*)d_in[0];
    const float* io     = (const float*)d_in[1];
    const float* cf     = (const float*)d_in[2];
    // d_in[3] cs_state: dead (does not feed y)
    const float* Wi2io  = (const float*)d_in[4];
    const float* bi2io  = (const float*)d_in[5];
    const float* Wio2o  = (const float*)d_in[6];
    const float* bio2o  = (const float*)d_in[7];
    const float* Wio2io = (const float*)d_in[8];
    const float* bio2io = (const float*)d_in[9];
    const float* Wcf2io = (const float*)d_in[12];
    const float* bcf2io = (const float*)d_in[13];
    float* out = (float*)d_out;

    // ws: wcat 1,179,648 | w2s 131,072 | bsum 2,048 | ionew 8,388,608
    char* ws = (char*)d_ws;
    unsigned short* wcat  = (unsigned short*)ws;
    unsigned short* w2s   = (unsigned short*)(ws + 1179648);
    float*          bsum  = (float*)(ws + 1310720);
    unsigned short* ionew = (unsigned short*)(ws + 1312768);

    hipLaunchKernelGGL(k_convert, dim3(642), dim3(256), 0, stream,
                       Wi2io, Wio2io, Wcf2io, Wio2o, bi2io, bio2io, bcf2io,
                       wcat, w2s, bsum);
    hipLaunchKernelGGL(k_gemm1, dim3(256), dim3(512), 0, stream,
                       x, io, cf, wcat, bsum, ionew);
    hipLaunchKernelGGL(k_gemm2, dim3(256), dim3(256), 0, stream,
                       ionew, w2s, bio2o, out);
}